// Round 1
// 224.137 us; speedup vs baseline: 1.1111x; 1.1111x over previous
//
#include <hip/hip_runtime.h>
#include <math.h>

// Problem constants (from reference)
#define N_NODES 50000
#define N_EDGES 800000
#define ET (N_EDGES + N_NODES)   // edges + self loops = 850000
#define IN_DIM 128
#define HID 128
#define OUT_DIM 64
#define BW 64                              // bucket width (dst nodes)
#define NBUCK ((N_NODES + BW - 1) / BW)    // 782 buckets
#define NBLK 256                           // partition blocks
#define EPB 3328                           // edges per partition block (13*256)
#define NT64 ((N_NODES + 63) / 64)         // 782 64-node tiles

typedef __attribute__((ext_vector_type(8))) short bf16x8;
typedef __attribute__((ext_vector_type(4))) float f32x4;

__device__ __forceinline__ float lrelu(float x){ return x >= 0.f ? x : 0.2f * x; }
__device__ __forceinline__ float eluf(float x){ return x > 0.f ? x : expm1f(x); }
// RNE float->bf16 (finite inputs)
__device__ __forceinline__ unsigned f2bf(float f){
    unsigned u = __float_as_uint(f);
    return (u + 0x7fffu + ((u >> 16) & 1u)) >> 16;
}
__device__ __forceinline__ float bflo(unsigned u){ return __uint_as_float(u << 16); }
__device__ __forceinline__ float bfhi(unsigned u){ return __uint_as_float(u & 0xffff0000u); }

// ---------------------------------------------------------------------------
// CSR build, atomic-free radix style.
// ---------------------------------------------------------------------------
__global__ __launch_bounds__(256) void k_count(const int* __restrict__ dst, int* __restrict__ C)
{
    __shared__ int cnt[NBUCK];
    const int tid = threadIdx.x, blk = blockIdx.x;
    for (int i = tid; i < NBUCK; i += 256) cnt[i] = 0;
    __syncthreads();
    #pragma unroll
    for (int j = 0; j < EPB / 256; j++) {
        const int e = blk * EPB + j * 256 + tid;
        if (e < ET) {
            const int d = (e < N_EDGES) ? dst[e] : (e - N_EDGES);
            atomicAdd(&cnt[d >> 6], 1);
        }
    }
    __syncthreads();
    for (int b = tid; b < NBUCK; b += 256) C[b * NBLK + blk] = cnt[b];
}

__global__ __launch_bounds__(256) void k_bsumA(const int* __restrict__ C, int* __restrict__ bsum2)
{
    __shared__ int red[4];
    int v = C[blockIdx.x * NBLK + threadIdx.x];
    #pragma unroll
    for (int off = 32; off > 0; off >>= 1) v += __shfl_down(v, off);
    if ((threadIdx.x & 63) == 0) red[threadIdx.x >> 6] = v;
    __syncthreads();
    if (threadIdx.x == 0) bsum2[blockIdx.x] = red[0] + red[1] + red[2] + red[3];
}

__global__ __launch_bounds__(1024) void k_bscanB(const int* __restrict__ bsum2, int* __restrict__ boff2)
{
    __shared__ int part[1024];
    const int t = threadIdx.x;
    int v = (t < NBUCK) ? bsum2[t] : 0;
    part[t] = v;
    __syncthreads();
    #pragma unroll
    for (int d = 1; d < 1024; d <<= 1) {
        int add = (t >= d) ? part[t - d] : 0;
        __syncthreads();
        part[t] += add;
        __syncthreads();
    }
    if (t < NBUCK) boff2[t] = part[t] - v;   // exclusive
    if (t == 0) boff2[NBUCK] = ET;
}

__global__ __launch_bounds__(256) void k_cscanC(const int* __restrict__ C,
                                                const int* __restrict__ boff2,
                                                int* __restrict__ Cs)
{
    __shared__ int part[256];
    const int t = threadIdx.x, b = blockIdx.x;
    int v = C[b * NBLK + t];
    part[t] = v;
    __syncthreads();
    #pragma unroll
    for (int d = 1; d < 256; d <<= 1) {
        int add = (t >= d) ? part[t - d] : 0;
        __syncthreads();
        part[t] += add;
        __syncthreads();
    }
    Cs[b * NBLK + t] = boff2[b] + part[t] - v;
}

// ---------------------------------------------------------------------------
// FAT KERNEL: blocks [0, NT64) = MFMA GEMM1 (h1 = x@W1, bf16 table + logits);
//             blocks [NT64, NT64+NBLK) = radix partition pass (independent).
// Overlaps the dense GEMM with the CSR scatter chain instead of serializing.
// ---------------------------------------------------------------------------
__global__ __launch_bounds__(256, 2) void k_gemm1_part2(
    const float* __restrict__ x, const float* __restrict__ W1,
    const float* __restrict__ a_s, const float* __restrict__ a_d,
    unsigned* __restrict__ h1b, float* __restrict__ as1, float* __restrict__ ad1,
    const int* __restrict__ src, const int* __restrict__ dst,
    const int* __restrict__ Cs, uint2* __restrict__ part)
{
    __shared__ unsigned smem[128 * 68 + 64 * 68];   // 52.2 KB, aliased by branch
    const int tid = threadIdx.x;

    if (blockIdx.x < NT64) {
        // ---------------- GEMM1 branch ----------------
        unsigned* sWt = smem;               // W^T bf16 pairs: [n][kp]
        unsigned* sxb = smem + 128 * 68;    // x   bf16 pairs: [node][kp]
        const int wave = tid >> 6;
        const int lane = tid & 63;
        const int ll   = lane & 15;
        const int quad = lane >> 4;
        const int n0 = blockIdx.x * 64;

        for (int idx = tid; idx < 8192; idx += 256) {
            const int n = idx & 127, kp = idx >> 7;
            const float w0 = W1[(2 * kp) * 128 + n];
            const float w1 = W1[(2 * kp + 1) * 128 + n];
            sWt[n * 68 + kp] = f2bf(w0) | (f2bf(w1) << 16);
        }
        for (int idx = tid; idx < 4096; idx += 256) {
            const int node = idx >> 6, kp = idx & 63;
            const int n = n0 + node;
            unsigned pk = 0;
            if (n < N_NODES) {
                const float x0 = x[n * 128 + 2 * kp];
                const float x1 = x[n * 128 + 2 * kp + 1];
                pk = f2bf(x0) | (f2bf(x1) << 16);
            }
            sxb[node * 68 + kp] = pk;
        }
        __syncthreads();

        f32x4 acc[8];
        #pragma unroll
        for (int t = 0; t < 8; t++) acc[t] = (f32x4){0.f, 0.f, 0.f, 0.f};

        #pragma unroll
        for (int kk = 0; kk < 4; kk++) {
            const int kpo = 16 * kk + 4 * quad;
            const bf16x8 a = *(const bf16x8*)&sxb[(16 * wave + ll) * 68 + kpo];
            #pragma unroll
            for (int t = 0; t < 8; t++) {
                const bf16x8 b = *(const bf16x8*)&sWt[(16 * t + ll) * 68 + kpo];
                acc[t] = __builtin_amdgcn_mfma_f32_16x16x32_bf16(a, b, acc[t], 0, 0, 0);
            }
        }

        float as_v[8], ad_v[8];
        #pragma unroll
        for (int t = 0; t < 8; t++) { as_v[t] = a_s[16 * t + ll]; ad_v[t] = a_d[16 * t + ll]; }
        unsigned short* h1u = (unsigned short*)h1b;
        #pragma unroll
        for (int r = 0; r < 4; r++) {
            const int n = n0 + 16 * wave + 4 * quad + r;
            float ps0 = acc[0][r] * as_v[0] + acc[1][r] * as_v[1];
            float ps1 = acc[2][r] * as_v[2] + acc[3][r] * as_v[3];
            float ps2 = acc[4][r] * as_v[4] + acc[5][r] * as_v[5];
            float ps3 = acc[6][r] * as_v[6] + acc[7][r] * as_v[7];
            float pd0 = acc[0][r] * ad_v[0] + acc[1][r] * ad_v[1];
            float pd1 = acc[2][r] * ad_v[2] + acc[3][r] * ad_v[3];
            float pd2 = acc[4][r] * ad_v[4] + acc[5][r] * ad_v[5];
            float pd3 = acc[6][r] * ad_v[6] + acc[7][r] * ad_v[7];
            #pragma unroll
            for (int off = 1; off < 16; off <<= 1) {
                ps0 += __shfl_xor(ps0, off); ps1 += __shfl_xor(ps1, off);
                ps2 += __shfl_xor(ps2, off); ps3 += __shfl_xor(ps3, off);
                pd0 += __shfl_xor(pd0, off); pd1 += __shfl_xor(pd1, off);
                pd2 += __shfl_xor(pd2, off); pd3 += __shfl_xor(pd3, off);
            }
            if (n < N_NODES) {
                #pragma unroll
                for (int t = 0; t < 8; t++)
                    h1u[n * 128 + 16 * t + ll] = (unsigned short)f2bf(acc[t][r]);
                if (ll == 0) {
                    as1[n * 4 + 0] = ps0; as1[n * 4 + 1] = ps1;
                    as1[n * 4 + 2] = ps2; as1[n * 4 + 3] = ps3;
                    ad1[n * 4 + 0] = pd0; ad1[n * 4 + 1] = pd1;
                    ad1[n * 4 + 2] = pd2; ad1[n * 4 + 3] = pd3;
                }
            }
        }
    } else {
        // ---------------- part2 branch ----------------
        const int blk = blockIdx.x - NT64;
        int* base = (int*)smem;
        int* cnt  = (int*)smem + NBUCK;
        for (int b = tid; b < NBUCK; b += 256) { base[b] = Cs[b * NBLK + blk]; cnt[b] = 0; }
        __syncthreads();
        #pragma unroll
        for (int j = 0; j < EPB / 256; j++) {
            const int e = blk * EPB + j * 256 + tid;
            if (e < ET) {
                int s, d;
                if (e < N_EDGES) { s = src[e]; d = dst[e]; } else { s = d = e - N_EDGES; }
                const int b = d >> 6;
                const int r = atomicAdd(&cnt[b], 1);
                part[base[b] + r] = make_uint2((unsigned)d, (unsigned)s);
            }
        }
    }
}

__global__ __launch_bounds__(256) void k_scat2(const int* __restrict__ boff2,
                                               const uint2* __restrict__ part,
                                               int* __restrict__ rowptr,
                                               int* __restrict__ csr_src)
{
    __shared__ int cnt64[BW];
    __shared__ int nbase[BW];
    const int b = blockIdx.x, tid = threadIdx.x;
    const int n0 = b * BW;
    const int lo = boff2[b], hi = boff2[b + 1];
    if (tid < BW) cnt64[tid] = 0;
    __syncthreads();
    for (int i = lo + tid; i < hi; i += 256) {
        atomicAdd(&cnt64[part[i].x & (BW - 1)], 1);
    }
    __syncthreads();
    if (tid < BW) {
        int v = cnt64[tid];
        int incl = v;
        #pragma unroll
        for (int off = 1; off < 64; off <<= 1) {
            int t2 = __shfl_up(incl, off);
            if (tid >= off) incl += t2;
        }
        const int excl = incl - v;
        nbase[tid] = excl;
        const int n = n0 + tid;
        if (n < N_NODES) rowptr[n] = lo + excl;
        cnt64[tid] = 0;
    }
    if (b == 0 && tid == 0) rowptr[N_NODES] = ET;
    __syncthreads();
    for (int i = lo + tid; i < hi; i += 256) {
        const uint2 p = part[i];
        const int dn = (int)p.x & (BW - 1);
        const int r = atomicAdd(&cnt64[dn], 1);
        csr_src[lo + nbase[dn] + r] = (int)p.y;
    }
}

// ---------------------------------------------------------------------------
// Aggregation layer 1: 16 threads/node, 8 channels each. Unroll-4 gather ILP.
// Fuses +b1 -> elu -> bf16 pack: writes layer-2 input table hEb [N][64] uints
// directly (halves intermediate traffic; arithmetic identical to the old
// acc1-fp32 round-trip since layer2 rounded to bf16 anyway).
// ---------------------------------------------------------------------------
__global__ __launch_bounds__(256) void k_aggr1(
    const int* __restrict__ rowptr, const int* __restrict__ csr_src,
    const float* __restrict__ as1, const float* __restrict__ ad1,
    const uint4* __restrict__ h1u4, const float* __restrict__ b1,
    unsigned* __restrict__ hEb)
{
    const int d  = blockIdx.x * 16 + (threadIdx.x >> 4);
    const int c8 = threadIdx.x & 15;
    const int hd = c8 >> 2;
    const int r0 = rowptr[d], r1 = rowptr[d + 1];
    const float adv = ad1[d * 4 + hd];
    float den = 0.f;
    float acc[8];
    #pragma unroll
    for (int m = 0; m < 8; m++) acc[m] = 0.f;
    int i = r0;
    for (; i + 4 <= r1; i += 4) {
        const int s0 = csr_src[i],     s1 = csr_src[i + 1];
        const int s2 = csr_src[i + 2], s3 = csr_src[i + 3];
        const float e0 = as1[s0 * 4 + hd], e1 = as1[s1 * 4 + hd];
        const float e2 = as1[s2 * 4 + hd], e3 = as1[s3 * 4 + hd];
        const uint4 u0 = h1u4[s0 * 16 + c8];
        const uint4 u1 = h1u4[s1 * 16 + c8];
        const uint4 u2 = h1u4[s2 * 16 + c8];
        const uint4 u3 = h1u4[s3 * 16 + c8];
        const float w0 = expf(lrelu(e0 + adv));
        const float w1 = expf(lrelu(e1 + adv));
        const float w2 = expf(lrelu(e2 + adv));
        const float w3 = expf(lrelu(e3 + adv));
        den += (w0 + w1) + (w2 + w3);
        acc[0] = fmaf(bflo(u0.x), w0, acc[0]); acc[1] = fmaf(bfhi(u0.x), w0, acc[1]);
        acc[2] = fmaf(bflo(u0.y), w0, acc[2]); acc[3] = fmaf(bfhi(u0.y), w0, acc[3]);
        acc[4] = fmaf(bflo(u0.z), w0, acc[4]); acc[5] = fmaf(bfhi(u0.z), w0, acc[5]);
        acc[6] = fmaf(bflo(u0.w), w0, acc[6]); acc[7] = fmaf(bfhi(u0.w), w0, acc[7]);
        acc[0] = fmaf(bflo(u1.x), w1, acc[0]); acc[1] = fmaf(bfhi(u1.x), w1, acc[1]);
        acc[2] = fmaf(bflo(u1.y), w1, acc[2]); acc[3] = fmaf(bfhi(u1.y), w1, acc[3]);
        acc[4] = fmaf(bflo(u1.z), w1, acc[4]); acc[5] = fmaf(bfhi(u1.z), w1, acc[5]);
        acc[6] = fmaf(bflo(u1.w), w1, acc[6]); acc[7] = fmaf(bfhi(u1.w), w1, acc[7]);
        acc[0] = fmaf(bflo(u2.x), w2, acc[0]); acc[1] = fmaf(bfhi(u2.x), w2, acc[1]);
        acc[2] = fmaf(bflo(u2.y), w2, acc[2]); acc[3] = fmaf(bfhi(u2.y), w2, acc[3]);
        acc[4] = fmaf(bflo(u2.z), w2, acc[4]); acc[5] = fmaf(bfhi(u2.z), w2, acc[5]);
        acc[6] = fmaf(bflo(u2.w), w2, acc[6]); acc[7] = fmaf(bfhi(u2.w), w2, acc[7]);
        acc[0] = fmaf(bflo(u3.x), w3, acc[0]); acc[1] = fmaf(bfhi(u3.x), w3, acc[1]);
        acc[2] = fmaf(bflo(u3.y), w3, acc[2]); acc[3] = fmaf(bfhi(u3.y), w3, acc[3]);
        acc[4] = fmaf(bflo(u3.z), w3, acc[4]); acc[5] = fmaf(bfhi(u3.z), w3, acc[5]);
        acc[6] = fmaf(bflo(u3.w), w3, acc[6]); acc[7] = fmaf(bfhi(u3.w), w3, acc[7]);
    }
    for (; i < r1; ++i) {
        const int s = csr_src[i];
        const float w = expf(lrelu(as1[s * 4 + hd] + adv));
        const uint4 u = h1u4[s * 16 + c8];
        den += w;
        acc[0] = fmaf(bflo(u.x), w, acc[0]); acc[1] = fmaf(bfhi(u.x), w, acc[1]);
        acc[2] = fmaf(bflo(u.y), w, acc[2]); acc[3] = fmaf(bfhi(u.y), w, acc[3]);
        acc[4] = fmaf(bflo(u.z), w, acc[4]); acc[5] = fmaf(bfhi(u.z), w, acc[5]);
        acc[6] = fmaf(bflo(u.w), w, acc[6]); acc[7] = fmaf(bfhi(u.w), w, acc[7]);
    }
    const float inv = 1.f / (den + 1e-16f);
    // channels 8*c8 .. 8*c8+7 ; apply bias + elu + pack bf16 pairs
    const float4 bA = ((const float4*)b1)[2 * c8];
    const float4 bB = ((const float4*)b1)[2 * c8 + 1];
    const float v0 = eluf(acc[0] * inv + bA.x);
    const float v1 = eluf(acc[1] * inv + bA.y);
    const float v2 = eluf(acc[2] * inv + bA.z);
    const float v3 = eluf(acc[3] * inv + bA.w);
    const float v4 = eluf(acc[4] * inv + bB.x);
    const float v5 = eluf(acc[5] * inv + bB.y);
    const float v6 = eluf(acc[6] * inv + bB.z);
    const float v7 = eluf(acc[7] * inv + bB.w);
    uint4 o;
    o.x = f2bf(v0) | (f2bf(v1) << 16);
    o.y = f2bf(v2) | (f2bf(v3) << 16);
    o.z = f2bf(v4) | (f2bf(v5) << 16);
    o.w = f2bf(v6) | (f2bf(v7) << 16);
    ((uint4*)hEb)[d * 16 + c8] = o;
}

// ---------------------------------------------------------------------------
// K4 (MFMA): h2 = hE @ W2 [N,64] -> bf16 table + logits. hE arrives already
// packed bf16 from k_aggr1 -> staging is a pure uint4 copy.
// ---------------------------------------------------------------------------
__global__ __launch_bounds__(256, 4) void k_layer2(
    const unsigned* __restrict__ hEb,
    const float* __restrict__ W2, const float* __restrict__ a_s2, const float* __restrict__ a_d2,
    unsigned* __restrict__ h2b, float* __restrict__ as2, float* __restrict__ ad2)
{
    __shared__ unsigned sWt[64 * 68];   // W2^T bf16 pairs [n][kp], 17.4 KB
    __shared__ unsigned sxb[64 * 68];   // hE   bf16 pairs [node][kp], 17.4 KB
    const int tid = threadIdx.x;
    const int wave = tid >> 6;
    const int lane = tid & 63;
    const int ll   = lane & 15;
    const int quad = lane >> 4;
    const int n0 = blockIdx.x * 64;

    // Stage W2^T: 4096 uints. n = idx&63 (coalesced W2 reads), kp = idx>>6.
    for (int idx = tid; idx < 4096; idx += 256) {
        const int n = idx & 63, kp = idx >> 6;
        const float w0 = W2[(2 * kp) * 64 + n];
        const float w1 = W2[(2 * kp + 1) * 64 + n];
        sWt[n * 68 + kp] = f2bf(w0) | (f2bf(w1) << 16);
    }
    // Stage hE: pure copy of pre-packed bf16 rows (uint4 loads).
    const uint4* hE4 = (const uint4*)hEb;
    for (int idx = tid; idx < 1024; idx += 256) {
        const int node = idx >> 4, q = idx & 15;
        const int n = n0 + node;
        uint4 pk = make_uint4(0, 0, 0, 0);
        if (n < N_NODES) pk = hE4[n * 16 + q];
        unsigned* dstp = &sxb[node * 68 + 4 * q];
        dstp[0] = pk.x; dstp[1] = pk.y; dstp[2] = pk.z; dstp[3] = pk.w;
    }
    __syncthreads();

    f32x4 acc[4];
    #pragma unroll
    for (int t = 0; t < 4; t++) acc[t] = (f32x4){0.f, 0.f, 0.f, 0.f};

    #pragma unroll
    for (int kk = 0; kk < 4; kk++) {
        const int kpo = 16 * kk + 4 * quad;
        const bf16x8 a = *(const bf16x8*)&sxb[(16 * wave + ll) * 68 + kpo];
        #pragma unroll
        for (int t = 0; t < 4; t++) {
            const bf16x8 b = *(const bf16x8*)&sWt[(16 * t + ll) * 68 + kpo];
            acc[t] = __builtin_amdgcn_mfma_f32_16x16x32_bf16(a, b, acc[t], 0, 0, 0);
        }
    }

    float as_v[4], ad_v[4];
    #pragma unroll
    for (int t = 0; t < 4; t++) { as_v[t] = a_s2[16 * t + ll]; ad_v[t] = a_d2[16 * t + ll]; }
    unsigned short* h2u = (unsigned short*)h2b;
    #pragma unroll
    for (int r = 0; r < 4; r++) {
        const int n = n0 + 16 * wave + 4 * quad + r;
        float ps = acc[0][r] * as_v[0] + acc[1][r] * as_v[1]
                 + acc[2][r] * as_v[2] + acc[3][r] * as_v[3];
        float pd = acc[0][r] * ad_v[0] + acc[1][r] * ad_v[1]
                 + acc[2][r] * ad_v[2] + acc[3][r] * ad_v[3];
        #pragma unroll
        for (int off = 1; off < 16; off <<= 1) {
            ps += __shfl_xor(ps, off);
            pd += __shfl_xor(pd, off);
        }
        if (n < N_NODES) {
            #pragma unroll
            for (int t = 0; t < 4; t++)
                h2u[n * 64 + 16 * t + ll] = (unsigned short)f2bf(acc[t][r]);
            if (ll == 0) { as2[n] = ps; ad2[n] = pd; }
        }
    }
}

// ---------------------------------------------------------------------------
// K_TAIL: aggregation layer 2 fused with the output MLP.
// 512 threads, 64 nodes/block, 782 blocks.
// Phase 1: 8 threads/node aggregate (unroll-4), apply +b2 -> elu, write the
//          MLP input tile straight into LDS (acc2 buffer eliminated).
// Phase 2: p = relu(so@pw1+pb1); out = p@pw2+pb2 (32 node-groups x 2 nodes).
// ---------------------------------------------------------------------------
__global__ __launch_bounds__(512, 4) void k_tail(
    const int* __restrict__ rowptr, const int* __restrict__ csr_src,
    const float* __restrict__ as2, const float* __restrict__ ad2,
    const uint4* __restrict__ h2u4, const float* __restrict__ b2,
    const float* __restrict__ pw1, const float* __restrict__ pb1,
    const float* __restrict__ pw2, const float* __restrict__ pb2,
    float* __restrict__ out)
{
    __shared__ float s1[64 * 64];    // pw1, 16 KB
    __shared__ float s2[64 * 64];    // pw2, 16 KB
    __shared__ float so[64][68];     // elu(agg + b2), 17.4 KB
    __shared__ float sp[64][68];     // relu hidden, 17.4 KB
    const int tid = threadIdx.x;
    const int n0 = blockIdx.x * 64;

    // Stage weights (consumed after the phase barrier).
    for (int i = tid; i < 1024; i += 512) {
        ((float4*)s1)[i] = ((const float4*)pw1)[i];
        ((float4*)s2)[i] = ((const float4*)pw2)[i];
    }

    // ---- Phase 1: aggregation (8 threads per node, 8 channels each) ----
    {
        const int dl = tid >> 3;        // 0..63
        const int c8 = tid & 7;
        const int d = n0 + dl;
        float acc[8];
        #pragma unroll
        for (int m = 0; m < 8; m++) acc[m] = 0.f;
        float v0 = 0.f, v1 = 0.f, v2 = 0.f, v3 = 0.f;
        float v4 = 0.f, v5 = 0.f, v6 = 0.f, v7 = 0.f;
        if (d < N_NODES) {
            const int r0 = rowptr[d], r1 = rowptr[d + 1];
            const float adv = ad2[d];
            float den = 0.f;
            int i = r0;
            for (; i + 4 <= r1; i += 4) {
                const int s0 = csr_src[i],     s1_ = csr_src[i + 1];
                const int s2_ = csr_src[i + 2], s3_ = csr_src[i + 3];
                const float e0 = as2[s0], e1 = as2[s1_], e2 = as2[s2_], e3 = as2[s3_];
                const uint4 u0 = h2u4[s0  * 8 + c8];
                const uint4 u1 = h2u4[s1_ * 8 + c8];
                const uint4 u2 = h2u4[s2_ * 8 + c8];
                const uint4 u3 = h2u4[s3_ * 8 + c8];
                const float w0 = expf(lrelu(e0 + adv));
                const float w1 = expf(lrelu(e1 + adv));
                const float w2 = expf(lrelu(e2 + adv));
                const float w3 = expf(lrelu(e3 + adv));
                den += (w0 + w1) + (w2 + w3);
                acc[0] = fmaf(bflo(u0.x), w0, acc[0]); acc[1] = fmaf(bfhi(u0.x), w0, acc[1]);
                acc[2] = fmaf(bflo(u0.y), w0, acc[2]); acc[3] = fmaf(bfhi(u0.y), w0, acc[3]);
                acc[4] = fmaf(bflo(u0.z), w0, acc[4]); acc[5] = fmaf(bfhi(u0.z), w0, acc[5]);
                acc[6] = fmaf(bflo(u0.w), w0, acc[6]); acc[7] = fmaf(bfhi(u0.w), w0, acc[7]);
                acc[0] = fmaf(bflo(u1.x), w1, acc[0]); acc[1] = fmaf(bfhi(u1.x), w1, acc[1]);
                acc[2] = fmaf(bflo(u1.y), w1, acc[2]); acc[3] = fmaf(bfhi(u1.y), w1, acc[3]);
                acc[4] = fmaf(bflo(u1.z), w1, acc[4]); acc[5] = fmaf(bfhi(u1.z), w1, acc[5]);
                acc[6] = fmaf(bflo(u1.w), w1, acc[6]); acc[7] = fmaf(bfhi(u1.w), w1, acc[7]);
                acc[0] = fmaf(bflo(u2.x), w2, acc[0]); acc[1] = fmaf(bfhi(u2.x), w2, acc[1]);
                acc[2] = fmaf(bflo(u2.y), w2, acc[2]); acc[3] = fmaf(bfhi(u2.y), w2, acc[3]);
                acc[4] = fmaf(bflo(u2.z), w2, acc[4]); acc[5] = fmaf(bfhi(u2.z), w2, acc[5]);
                acc[6] = fmaf(bflo(u2.w), w2, acc[6]); acc[7] = fmaf(bfhi(u2.w), w2, acc[7]);
                acc[0] = fmaf(bflo(u3.x), w3, acc[0]); acc[1] = fmaf(bfhi(u3.x), w3, acc[1]);
                acc[2] = fmaf(bflo(u3.y), w3, acc[2]); acc[3] = fmaf(bfhi(u3.y), w3, acc[3]);
                acc[4] = fmaf(bflo(u3.z), w3, acc[4]); acc[5] = fmaf(bfhi(u3.z), w3, acc[5]);
                acc[6] = fmaf(bflo(u3.w), w3, acc[6]); acc[7] = fmaf(bfhi(u3.w), w3, acc[7]);
            }
            for (; i < r1; ++i) {
                const int s = csr_src[i];
                const float w = expf(lrelu(as2[s] + adv));
                const uint4 u = h2u4[s * 8 + c8];
                den += w;
                acc[0] = fmaf(bflo(u.x), w, acc[0]); acc[1] = fmaf(bfhi(u.x), w, acc[1]);
                acc[2] = fmaf(bflo(u.y), w, acc[2]); acc[3] = fmaf(bfhi(u.y), w, acc[3]);
                acc[4] = fmaf(bflo(u.z), w, acc[4]); acc[5] = fmaf(bfhi(u.z), w, acc[5]);
                acc[6] = fmaf(bflo(u.w), w, acc[6]); acc[7] = fmaf(bfhi(u.w), w, acc[7]);
            }
            const float inv = 1.f / (den + 1e-16f);
            const float4 bA = ((const float4*)b2)[2 * c8];
            const float4 bB = ((const float4*)b2)[2 * c8 + 1];
            v0 = eluf(acc[0] * inv + bA.x);
            v1 = eluf(acc[1] * inv + bA.y);
            v2 = eluf(acc[2] * inv + bA.z);
            v3 = eluf(acc[3] * inv + bA.w);
            v4 = eluf(acc[4] * inv + bB.x);
            v5 = eluf(acc[5] * inv + bB.y);
            v6 = eluf(acc[6] * inv + bB.z);
            v7 = eluf(acc[7] * inv + bB.w);
        }
        *(float4*)&so[dl][8 * c8]     = make_float4(v0, v1, v2, v3);
        *(float4*)&so[dl][8 * c8 + 4] = make_float4(v4, v5, v6, v7);
    }
    __syncthreads();

    // ---- Phase 2: 2-layer MLP on the 64-node tile ----
    const int cg = tid & 15;          // column group (4 cols)
    const int ng = tid >> 4;          // 0..31, 2 nodes each
    const float4 pb1_4 = ((const float4*)pb1)[cg];
    const float4 pb2_4 = ((const float4*)pb2)[cg];
    float4 p[2];
    #pragma unroll
    for (int m = 0; m < 2; m++) p[m] = pb1_4;
    #pragma unroll 8
    for (int k = 0; k < 64; k++) {
        const float4 w = *(const float4*)&s1[k * 64 + 4 * cg];
        #pragma unroll
        for (int m = 0; m < 2; m++) {
            const float xv = so[2 * ng + m][k];
            p[m].x = fmaf(xv, w.x, p[m].x);
            p[m].y = fmaf(xv, w.y, p[m].y);
            p[m].z = fmaf(xv, w.z, p[m].z);
            p[m].w = fmaf(xv, w.w, p[m].w);
        }
    }
    #pragma unroll
    for (int m = 0; m < 2; m++) {
        p[m].x = fmaxf(p[m].x, 0.f); p[m].y = fmaxf(p[m].y, 0.f);
        p[m].z = fmaxf(p[m].z, 0.f); p[m].w = fmaxf(p[m].w, 0.f);
        *(float4*)&sp[2 * ng + m][4 * cg] = p[m];
    }
    __syncthreads();
    float4 o[2];
    #pragma unroll
    for (int m = 0; m < 2; m++) o[m] = pb2_4;
    #pragma unroll 8
    for (int k = 0; k < 64; k++) {
        const float4 w = *(const float4*)&s2[k * 64 + 4 * cg];
        #pragma unroll
        for (int m = 0; m < 2; m++) {
            const float xv = sp[2 * ng + m][k];
            o[m].x = fmaf(xv, w.x, o[m].x);
            o[m].y = fmaf(xv, w.y, o[m].y);
            o[m].z = fmaf(xv, w.z, o[m].z);
            o[m].w = fmaf(xv, w.w, o[m].w);
        }
    }
    #pragma unroll
    for (int m = 0; m < 2; m++) {
        const int n = n0 + 2 * ng + m;
        if (n < N_NODES) ((float4*)out)[n * 16 + cg] = o[m];
    }
}

// ---------------------------------------------------------------------------
extern "C" void kernel_launch(void* const* d_in, const int* in_sizes, int n_in,
                              void* d_out, int out_size, void* d_ws, size_t ws_size,
                              hipStream_t stream)
{
    const float* x      = (const float*)d_in[0];
    const int*   ei     = (const int*)d_in[1];   // [2, E] int32
    const int*   src    = ei;
    const int*   dst    = ei + N_EDGES;
    const float* W1     = (const float*)d_in[2];
    const float* a_src1 = (const float*)d_in[3];
    const float* a_dst1 = (const float*)d_in[4];
    const float* b1     = (const float*)d_in[5];
    const float* W2     = (const float*)d_in[6];
    const float* a_src2 = (const float*)d_in[7];
    const float* a_dst2 = (const float*)d_in[8];
    const float* b2     = (const float*)d_in[9];
    const float* pw1    = (const float*)d_in[10];
    const float* pb1    = (const float*)d_in[11];
    const float* pw2    = (const float*)d_in[12];
    const float* pb2    = (const float*)d_in[13];

    // Workspace layout. part first (8B align from d_ws base).
    uint2* part  = (uint2*)d_ws;          // ET uint2
    int* ibase   = (int*)(part + ET);
    int* rowptr  = ibase;                 // 50,001
    int* C       = rowptr + 50001;        // NBUCK*NBLK = 200,192
    int* Cs      = C + 200192;            // 200,192
    int* bsum2   = Cs + 200192;           // 782
    int* boff2   = bsum2 + 782;           // 783 (+2 pad -> 785)
    int* csr_src = boff2 + 785;           // 850,000
    unsigned* h1b = (unsigned*)(csr_src + 850000);  // N*64 uints (bf16 x2)
    unsigned* h2b = h1b + 3200000;                  // N*32 uints
    float* fws   = (float*)(h2b + 1600000);
    float* as1   = fws;                   // N*4
    float* ad1   = as1 + 200000;          // N*4
    unsigned* hEb = (unsigned*)(ad1 + 200000);      // N*64 uints (elu'd bf16)
    float* as2   = (float*)(hEb + 3200000);         // N
    float* ad2   = as2 + 50000;                     // N

    // CSR build — atomic-free radix partition (reused by both layers).
    k_count<<<NBLK, 256, 0, stream>>>(dst, C);
    k_bsumA<<<NBUCK, 256, 0, stream>>>(C, bsum2);
    k_bscanB<<<1, 1024, 0, stream>>>(bsum2, boff2);
    k_cscanC<<<NBUCK, 256, 0, stream>>>(C, boff2, Cs);

    // GEMM1 overlapped with the partition pass (independent work, one launch).
    k_gemm1_part2<<<NT64 + NBLK, 256, 0, stream>>>(x, W1, a_src1, a_dst1,
                                                   h1b, as1, ad1,
                                                   src, dst, Cs, part);
    k_scat2<<<NBUCK, 256, 0, stream>>>(boff2, part, rowptr, csr_src);

    // Layer 1 aggregation (writes elu'd bf16 layer-2 input directly).
    k_aggr1<<<N_NODES / 16, 256, 0, stream>>>(rowptr, csr_src, as1, ad1,
                                              (const uint4*)h1b, b1, hEb);

    // Layer 2 (MFMA GEMM)
    k_layer2<<<NT64, 256, 0, stream>>>(hEb, W2, a_src2, a_dst2, h2b, as2, ad2);

    // Layer 2 aggregation + output MLP, fused.
    k_tail<<<NT64, 512, 0, stream>>>(rowptr, csr_src, as2, ad2,
                                     (const uint4*)h2b, b2,
                                     pw1, pb1, pw2, pb2, (float*)d_out);
}